// Round 10
// baseline (136.037 us; speedup 1.0000x reference)
//
#include <hip/hip_runtime.h>

#define MODS 4
#define CH   128
#define NHD  4
#define HDIM 32
#define NTOK 1728
#define NG   (NTOK/4)
#define NKEY (MODS*NTOK)        // 6912
#define NT   27                 // 32-key tiles per 864-key segment
// Q is pre-scaled by 1/sqrt(32) * log2(e) so softmax is exp2(S) directly.
#define QSC (0.17677669529663687f * 1.4426950408889634f)

#ifndef __has_builtin
#define __has_builtin(x) 0
#endif
#if __has_builtin(__builtin_amdgcn_exp2f)
#define EXP2(x) __builtin_amdgcn_exp2f(x)
#else
#define EXP2(x) __expf(0.69314718055994531f * (x))
#endif

typedef __bf16 bf16x8 __attribute__((ext_vector_type(8)));
typedef float  f32x16 __attribute__((ext_vector_type(16)));

__device__ inline bf16x8 ldb8(const unsigned short* p) {
    return *reinterpret_cast<const bf16x8*>(p);
}
__device__ inline unsigned int pkbf(float a, float b) {
    unsigned short ua = __builtin_bit_cast(unsigned short, (__bf16)a);
    unsigned short ub = __builtin_bit_cast(unsigned short, (__bf16)b);
    return (unsigned int)ua | ((unsigned int)ub << 16);
}
// async global->LDS, 16B per lane; LDS dest = uniform base + lane*16
__device__ inline void glds16(const unsigned short* g, unsigned short* l) {
    __builtin_amdgcn_global_load_lds(
        (const __attribute__((address_space(1))) unsigned int*)(g),
        (__attribute__((address_space(3))) unsigned int*)(l), 16, 0, 0);
}

// ---------------------------------------------------------------------------
// Kernel 1: LDS-tiled QKV projection (fp32 math, bf16 out), c-split halves.
// Qb/Kb: bf16 [m][h][n][32] (Q pre-scaled by QSC).
// V2: bf16 [h][32d][key], keys fragment-ordered per 16-window:
//     4-key group at offset {0,4,8,12} stored at position {0,8,4,12}.
// ---------------------------------------------------------------------------
__global__ __launch_bounds__(256) void proj_kernel(
    const float* __restrict__ f0, const float* __restrict__ f1,
    const float* __restrict__ f2, const float* __restrict__ f3,
    const float* __restrict__ Wq, const float* __restrict__ Wk,
    const float* __restrict__ Wv,
    unsigned short* __restrict__ Qb, unsigned short* __restrict__ Kb,
    unsigned short* __restrict__ V2)
{
    __shared__ __align__(16) float Wt[64][68];   // 17 KB
    __shared__ __align__(16) float fs[64][68];   // 17 KB

    const int tid = threadIdx.x;
    const int bid = blockIdx.x;
    const int tm  = bid / 54;
    const int rem = bid % 54;
    const int oh  = rem & 1;
    const int nt  = rem >> 1;
    const int t   = tm >> 2, m = tm & 3;
    const int nb  = nt * 64;

    const float* fsrc = (m == 0) ? f0 : (m == 1) ? f1 : (m == 2) ? f2 : f3;
    const float* W    = ((t == 0) ? Wq : (t == 1) ? Wk : Wv) + (size_t)m * CH * CH;

    const int o0 = (tid >> 4) * 4, nn0 = (tid & 15) * 4;
    float acc[4][4] = {};

    for (int ch = 0; ch < 2; ++ch) {
        if (ch) __syncthreads();
        {
            const int o = tid & 63, c4b = tid >> 6;
            #pragma unroll
            for (int j = 0; j < 4; ++j) {
                const int c4 = c4b + 4 * j;
                float4 wv = *reinterpret_cast<const float4*>(
                    W + (size_t)(oh * 64 + o) * CH + ch * 64 + c4 * 4);
                Wt[c4*4+0][o] = wv.x; Wt[c4*4+1][o] = wv.y;
                Wt[c4*4+2][o] = wv.z; Wt[c4*4+3][o] = wv.w;
            }
        }
        {
            const int nchunk = tid & 15, cb = tid >> 4;
            #pragma unroll
            for (int j = 0; j < 4; ++j) {
                const int c = cb + 16 * j;
                float4 v = *reinterpret_cast<const float4*>(
                    fsrc + (size_t)(ch * 64 + c) * NTOK + nb + nchunk * 4);
                *reinterpret_cast<float4*>(&fs[c][nchunk * 4]) = v;
            }
        }
        __syncthreads();
        #pragma unroll 4
        for (int c = 0; c < 64; ++c) {
            float4 wv = *reinterpret_cast<const float4*>(&Wt[c][o0]);
            float4 fv = *reinterpret_cast<const float4*>(&fs[c][nn0]);
            acc[0][0] = fmaf(wv.x, fv.x, acc[0][0]); acc[0][1] = fmaf(wv.x, fv.y, acc[0][1]);
            acc[0][2] = fmaf(wv.x, fv.z, acc[0][2]); acc[0][3] = fmaf(wv.x, fv.w, acc[0][3]);
            acc[1][0] = fmaf(wv.y, fv.x, acc[1][0]); acc[1][1] = fmaf(wv.y, fv.y, acc[1][1]);
            acc[1][2] = fmaf(wv.y, fv.z, acc[1][2]); acc[1][3] = fmaf(wv.y, fv.w, acc[1][3]);
            acc[2][0] = fmaf(wv.z, fv.x, acc[2][0]); acc[2][1] = fmaf(wv.z, fv.y, acc[2][1]);
            acc[2][2] = fmaf(wv.z, fv.z, acc[2][2]); acc[2][3] = fmaf(wv.z, fv.w, acc[2][3]);
            acc[3][0] = fmaf(wv.w, fv.x, acc[3][0]); acc[3][1] = fmaf(wv.w, fv.y, acc[3][1]);
            acc[3][2] = fmaf(wv.w, fv.z, acc[3][2]); acc[3][3] = fmaf(wv.w, fv.w, acc[3][3]);
        }
    }

    const int og0 = oh * 64 + o0;
    const int h = og0 >> 5, d0 = og0 & 31;
    const int ng = nb + nn0;
    if (t == 2) {
        const int off = ng & 15;                      // 0,4,8,12
        const int ng2 = (ng & ~15) + ((off & 4) << 1) + ((off & 8) >> 1);
        #pragma unroll
        for (int i = 0; i < 4; ++i) {
            ushort4 pk;
            pk.x = __builtin_bit_cast(unsigned short, (__bf16)acc[i][0]);
            pk.y = __builtin_bit_cast(unsigned short, (__bf16)acc[i][1]);
            pk.z = __builtin_bit_cast(unsigned short, (__bf16)acc[i][2]);
            pk.w = __builtin_bit_cast(unsigned short, (__bf16)acc[i][3]);
            *reinterpret_cast<ushort4*>(V2 + (size_t)(h * HDIM + d0 + i) * NKEY + m * NTOK + ng2) = pk;
        }
    } else {
        const float sc = (t == 0) ? QSC : 1.0f;
        unsigned short* base = ((t == 0) ? Qb : Kb)
            + (((size_t)(m * NHD + h)) * NTOK + ng) * HDIM + d0;
        #pragma unroll
        for (int j = 0; j < 4; ++j) {
            unsigned short* row = base + (size_t)j * HDIM;
            *reinterpret_cast<unsigned int*>(row)     = pkbf(acc[0][j] * sc, acc[1][j] * sc);
            *reinterpret_cast<unsigned int*>(row + 2) = pkbf(acc[2][j] * sc, acc[3][j] * sc);
        }
    }
}

// ---------------------------------------------------------------------------
// Kernel 2: MFMA cross-modal attention, 1728 blocks x 4 waves (256 thr).
// bid: slot=bid&7 -> (h=slot>>1, ko=slot&1) [XCD-pinned]; rest=bid>>3:
// qb=rest%108, kseg=rest/108. Wave w: qslot=w&1 (qtile=qb*2+qslot),
// ks=w>>1 (modality km=2ko+ks); keys [kseg*864, +864) = 27 tiles x 32 keys.
// 16 KB LDS (2buf x 2ks x (K 1KB + V 1KB)) -> ~6.75 blocks/CU resident =
// ~27 waves/CU (2x R9) for latency hiding. R7/R9-style compiler-managed
// loop: STAGE(next) -> compute(cur) -> __syncthreads (1 barrier/tile).
// Swizzles re-derived for 64B rows (bank-enumerated, at b128 floor):
//   K LDS [32 key][4 c16]: chunk ^= (key>>1)&3
//   V LDS [32 d ][4 c16]: chunk ^= d&3
// pre-applied on glds SOURCE, involution on ds_read. MFMA pairing and
// ones-B denominator (s_acc) identical to verified R9. Max-free exp2.
// Partials p = kseg*2+ko (4 per q-row) -> accT/sR; norm combines.
// ---------------------------------------------------------------------------
__global__ __launch_bounds__(256, 8) void attn_kernel(
    const unsigned short* __restrict__ Qb, const unsigned short* __restrict__ Kb,
    const unsigned short* __restrict__ V2,
    float* __restrict__ accT, float* __restrict__ sR)
{
    __shared__ __align__(16) unsigned short smAll[2][2][2][1024]; // [buf][ks][K/V] 16 KB

    const int tid  = threadIdx.x;
    const int lane = tid & 63;
    const int w    = tid >> 6;        // 0..3
    const int qslot = w & 1;
    const int ks    = w >> 1;
    const int l31  = lane & 31;
    const int hi   = lane >> 5;

    const int bid  = blockIdx.x;
    const int slot = bid & 7;              // XCD slot
    const int h    = slot >> 1;
    const int ko   = slot & 1;
    const int rest = bid >> 3;             // 0..215
    const int qb   = rest % 108;
    const int kseg = rest / 108;           // 0..1
    const int qtile = qb * 2 + qslot;      // 0..215
    const int qg0  = qtile * 32;
    const int im   = qg0 / NTOK;
    const int n0   = qg0 % NTOK;
    const int km   = ko * 2 + ks;
    const int p    = kseg * 2 + ko;        // partial slot 0..3

    // Q fragments (pre-scaled by QSC)
    const unsigned short* qp = Qb + (((size_t)(im * NHD + h)) * NTOK + n0 + l31) * HDIM + hi * 8;
    const bf16x8 qf0 = ldb8(qp);
    const bf16x8 qf1 = ldb8(qp + 16);

    // --- staging sources (this wave's 2 glds per tile, inverse-swizzled) ---
    const int rk0 = qslot * 16 + (lane >> 2);            // K tile row (key)
    const int ck0 = (lane & 3) ^ ((rk0 >> 1) & 3);
    const unsigned short* gk0 = Kb
        + (((size_t)(km * NHD + h)) * NTOK + kseg * 864 + rk0) * HDIM + ck0 * 8;
    const int dv0 = qslot * 16 + (lane >> 2);            // V tile row (d)
    const int cv0 = (lane & 3) ^ (dv0 & 3);
    const unsigned short* gv0 = V2
        + ((size_t)(h * HDIM + dv0)) * NKEY + km * NTOK + kseg * 864 + cv0 * 8;

    // --- LDS read offsets (shorts), swizzle involution applied ---
    const int fK = (l31 >> 1) & 3, fV = l31 & 3;
    const int kA0 = l31 * 32 + ((hi ^ fK) << 3);
    const int kB0 = l31 * 32 + (((2 + hi) ^ fK) << 3);
    const int vo0 = l31 * 32 + ((hi ^ fV) << 3);
    const int vo1 = l31 * 32 + (((2 + hi) ^ fV) << 3);

    f32x16 z;
    #pragma unroll
    for (int r = 0; r < 16; ++r) z[r] = 0.f;
    f32x16 o_acc = z, s_acc = z;
    bf16x8 onesv;
    #pragma unroll
    for (int j = 0; j < 8; ++j) onesv[j] = (__bf16)1.0f;

    // stage next tile into buffer bb (2 glds; pointers advance)
    #define STAGE(bb) do {                                      \
        glds16(gk0, &smAll[bb][ks][0][0] + qslot * 512);        \
        glds16(gv0, &smAll[bb][ks][1][0] + qslot * 512);        \
        gk0 += 1024; gv0 += 32;                                 \
    } while (0)

    STAGE(0);                 // tile 0
    __syncthreads();

    int buf = 0;
    for (int t = 0; t < NT; ++t) {
        if (t + 1 < NT) STAGE(buf ^ 1);
        const unsigned short* Kl = &smAll[buf][ks][0][0];
        const unsigned short* Vl = &smAll[buf][ks][1][0];

        bf16x8 k0 = ldb8(Kl + kA0);
        bf16x8 k1 = ldb8(Kl + kB0);
        f32x16 c = __builtin_amdgcn_mfma_f32_32x32x16_bf16(k0, qf0, z, 0, 0, 0);
        c = __builtin_amdgcn_mfma_f32_32x32x16_bf16(k1, qf1, c, 0, 0, 0);

        float e[16];
        #pragma unroll
        for (int r = 0; r < 16; ++r) e[r] = EXP2(c[r]);
        bf16x8 pa0, pa1;
        #pragma unroll
        for (int j = 0; j < 8; ++j) { pa0[j] = (__bf16)e[j]; pa1[j] = (__bf16)e[8 + j]; }

        bf16x8 v0 = ldb8(Vl + vo0);
        bf16x8 v1 = ldb8(Vl + vo1);

        o_acc = __builtin_amdgcn_mfma_f32_32x32x16_bf16(pa0, v0, o_acc, 0, 0, 0);
        o_acc = __builtin_amdgcn_mfma_f32_32x32x16_bf16(pa1, v1, o_acc, 0, 0, 0);
        s_acc = __builtin_amdgcn_mfma_f32_32x32x16_bf16(pa0, onesv, s_acc, 0, 0, 0);
        s_acc = __builtin_amdgcn_mfma_f32_32x32x16_bf16(pa1, onesv, s_acc, 0, 0, 0);

        __syncthreads();
        buf ^= 1;
    }
    #undef STAGE

    // --- epilogue: combine ks pair in LDS [64 q][33] (s in col 32) ---
    float* accf = (float*)&smAll[0][0][0][0];    // 64*33*4 = 8.4 KB (reuse)
    if (ks == 1) {
        #pragma unroll
        for (int r = 0; r < 16; ++r) {
            const int qrow = (r & 3) + 8 * (r >> 2) + 4 * hi;
            accf[(qslot * 32 + qrow) * 33 + l31] = o_acc[r];
            if (l31 == 0) accf[(qslot * 32 + qrow) * 33 + 32] = s_acc[r];
        }
    }
    __syncthreads();
    if (ks == 0) {
        #pragma unroll
        for (int r = 0; r < 16; ++r) {
            const int qrow = (r & 3) + 8 * (r >> 2) + 4 * hi;
            accf[(qslot * 32 + qrow) * 33 + l31] += o_acc[r];
            if (l31 == 0) accf[(qslot * 32 + qrow) * 33 + 32] += s_acc[r];
        }
    }
    __syncthreads();
    {
        const int q  = tid & 63;
        const int dq = tid >> 6;      // 0..3
        #pragma unroll
        for (int j = 0; j < 8; ++j) {
            const int d = dq * 8 + j;
            accT[((size_t)((p * 4 + h) * HDIM + d)) * NKEY + (size_t)qb * 64 + q]
                = accf[q * 33 + d];
        }
        if (tid < 64)
            sR[((size_t)(p * 4 + h)) * NKEY + (size_t)qb * 64 + tid] = accf[tid * 33 + 32];
    }
}

// ---------------------------------------------------------------------------
// Kernel 3: combine 4 key-partials + normalize + modality-sum.
// ---------------------------------------------------------------------------
__global__ __launch_bounds__(256) void norm_kernel(
    const float* __restrict__ accT, const float* __restrict__ sR,
    float* __restrict__ fused)
{
    const int idx = blockIdx.x * 256 + threadIdx.x;  // 0 .. 128*1728-1
    const int c = idx / NTOK;
    const int n = idx % NTOK;
    const int h = c >> 5, d = c & 31;
    float acc = 0.f;
    #pragma unroll
    for (int imq = 0; imq < MODS; ++imq) {
        const size_t q = (size_t)imq * NTOK + n;
        float s = 0.f, a = 0.f;
        #pragma unroll
        for (int pp = 0; pp < 4; ++pp) {
            s += sR[(size_t)(pp * 4 + h) * NKEY + q];
            a += accT[((size_t)((pp * 4 + h) * HDIM + d)) * NKEY + q];
        }
        acc = fmaf(a, 1.0f / s, acc);
    }
    fused[idx] = acc;
}

// ---------------------------------------------------------------------------
// Kernel 4: out-proj (Wout @ fused) + BatchNorm(eval) + ReLU, 2 tokens/thread
// ---------------------------------------------------------------------------
__global__ __launch_bounds__(256) void outproj_kernel(
    const float* __restrict__ fused, const float* __restrict__ Wout,
    const float* __restrict__ gamma, const float* __restrict__ beta,
    const float* __restrict__ mean,  const float* __restrict__ var,
    float* __restrict__ out)
{
    const int idx = blockIdx.x * 256 + threadIdx.x;  // 0 .. 128*864-1
    const int n2 = idx % (NTOK / 2);
    const int o  = idx / (NTOK / 2);
    const float* W     = Wout + (size_t)o * CH;
    const float* fbase = fused + n2 * 2;
    float a0 = 0.f, a1 = 0.f;
    #pragma unroll 8
    for (int c = 0; c < CH; c += 4) {
        float4 w4 = *reinterpret_cast<const float4*>(W + c);
        float2 r0 = *reinterpret_cast<const float2*>(fbase + (size_t)(c + 0) * NTOK);
        float2 r1 = *reinterpret_cast<const float2*>(fbase + (size_t)(c + 1) * NTOK);
        float2 r2 = *reinterpret_cast<const float2*>(fbase + (size_t)(c + 2) * NTOK);
        float2 r3 = *reinterpret_cast<const float2*>(fbase + (size_t)(c + 3) * NTOK);
        a0 = fmaf(w4.x, r0.x, a0); a0 = fmaf(w4.y, r1.x, a0);
        a0 = fmaf(w4.z, r2.x, a0); a0 = fmaf(w4.w, r3.x, a0);
        a1 = fmaf(w4.x, r0.y, a1); a1 = fmaf(w4.y, r1.y, a1);
        a1 = fmaf(w4.z, r2.y, a1); a1 = fmaf(w4.w, r3.y, a1);
    }
    float inv = gamma[o] * rsqrtf(var[o] + 1e-5f);
    float sh  = fmaf(-mean[o], inv, beta[o]);
    float2 y;
    y.x = fmaxf(fmaf(a0, inv, sh), 0.f);
    y.y = fmaxf(fmaf(a1, inv, sh), 0.f);
    *reinterpret_cast<float2*>(out + (size_t)o * NTOK + n2 * 2) = y;
}

// ---------------------------------------------------------------------------
extern "C" void kernel_launch(void* const* d_in, const int* in_sizes, int n_in,
                              void* d_out, int out_size, void* d_ws, size_t ws_size,
                              hipStream_t stream)
{
    const float* f0    = (const float*)d_in[0];
    const float* f1    = (const float*)d_in[1];
    const float* f2    = (const float*)d_in[2];
    const float* f3    = (const float*)d_in[3];
    const float* Wq    = (const float*)d_in[4];
    const float* Wk    = (const float*)d_in[5];
    const float* Wv    = (const float*)d_in[6];
    const float* Wout  = (const float*)d_in[7];
    const float* gamma = (const float*)d_in[8];
    const float* beta  = (const float*)d_in[9];
    const float* mean  = (const float*)d_in[10];
    const float* var   = (const float*)d_in[11];
    float* out = (float*)d_out;

    const size_t QKV = (size_t)MODS * NHD * NTOK * HDIM;   // 884736 elems
    unsigned short* Qb = (unsigned short*)d_ws;
    unsigned short* Kb = Qb + QKV;
    unsigned short* V2 = Kb + QKV;
    float* accT  = (float*)(V2 + QKV);          // [4p*4h*32d][6912 q] f32
    float* sR    = accT + (size_t)4 * NHD * HDIM * NKEY;   // [16][6912]
    float* fused = sR + (size_t)4 * NHD * NKEY;            // [CH][NTOK]

    proj_kernel<<<648, 256, 0, stream>>>(f0, f1, f2, f3, Wq, Wk, Wv, Qb, Kb, V2);
    attn_kernel<<<1728, 256, 0, stream>>>(Qb, Kb, V2, accT, sR);
    norm_kernel<<<(CH * NTOK) / 256, 256, 0, stream>>>(accT, sR, fused);
    outproj_kernel<<<(CH * NTOK / 2) / 256, 256, 0, stream>>>(
        fused, Wout, gamma, beta, mean, var, out);
}

// Round 11
// 77.935 us; speedup vs baseline: 1.7455x; 1.7455x over previous
//
#include <hip/hip_runtime.h>

#define MODS 4
#define CH   128
#define NHD  4
#define HDIM 32
#define NTOK 1728
#define NG   (NTOK/4)
#define NKEY (MODS*NTOK)        // 6912
#define NT   27                 // 32-key tiles per 864-key segment
// Q is pre-scaled by 1/sqrt(32) * log2(e) so softmax is exp2(S) directly.
#define QSC (0.17677669529663687f * 1.4426950408889634f)

#ifndef __has_builtin
#define __has_builtin(x) 0
#endif
#if __has_builtin(__builtin_amdgcn_exp2f)
#define EXP2(x) __builtin_amdgcn_exp2f(x)
#else
#define EXP2(x) __expf(0.69314718055994531f * (x))
#endif

typedef __bf16 bf16x8 __attribute__((ext_vector_type(8)));
typedef float  f32x16 __attribute__((ext_vector_type(16)));

__device__ inline bf16x8 ldb8(const unsigned short* p) {
    return *reinterpret_cast<const bf16x8*>(p);
}
__device__ inline unsigned int pkbf(float a, float b) {
    unsigned short ua = __builtin_bit_cast(unsigned short, (__bf16)a);
    unsigned short ub = __builtin_bit_cast(unsigned short, (__bf16)b);
    return (unsigned int)ua | ((unsigned int)ub << 16);
}
// async global->LDS, 16B per lane; LDS dest = uniform base + lane*16
__device__ inline void glds16(const unsigned short* g, unsigned short* l) {
    __builtin_amdgcn_global_load_lds(
        (const __attribute__((address_space(1))) unsigned int*)(g),
        (__attribute__((address_space(3))) unsigned int*)(l), 16, 0, 0);
}

// ---------------------------------------------------------------------------
// Kernel 1: LDS-tiled QKV projection (fp32 math, bf16 out), c-split halves.
// Qb/Kb: bf16 [m][h][n][32] (Q pre-scaled by QSC).
// V2: bf16 [h][32d][key], keys fragment-ordered per 16-window:
//     4-key group at offset {0,4,8,12} stored at position {0,8,4,12}.
// ---------------------------------------------------------------------------
__global__ __launch_bounds__(256) void proj_kernel(
    const float* __restrict__ f0, const float* __restrict__ f1,
    const float* __restrict__ f2, const float* __restrict__ f3,
    const float* __restrict__ Wq, const float* __restrict__ Wk,
    const float* __restrict__ Wv,
    unsigned short* __restrict__ Qb, unsigned short* __restrict__ Kb,
    unsigned short* __restrict__ V2)
{
    __shared__ __align__(16) float Wt[64][68];   // 17 KB
    __shared__ __align__(16) float fs[64][68];   // 17 KB

    const int tid = threadIdx.x;
    const int bid = blockIdx.x;
    const int tm  = bid / 54;
    const int rem = bid % 54;
    const int oh  = rem & 1;
    const int nt  = rem >> 1;
    const int t   = tm >> 2, m = tm & 3;
    const int nb  = nt * 64;

    const float* fsrc = (m == 0) ? f0 : (m == 1) ? f1 : (m == 2) ? f2 : f3;
    const float* W    = ((t == 0) ? Wq : (t == 1) ? Wk : Wv) + (size_t)m * CH * CH;

    const int o0 = (tid >> 4) * 4, nn0 = (tid & 15) * 4;
    float acc[4][4] = {};

    for (int ch = 0; ch < 2; ++ch) {
        if (ch) __syncthreads();
        {
            const int o = tid & 63, c4b = tid >> 6;
            #pragma unroll
            for (int j = 0; j < 4; ++j) {
                const int c4 = c4b + 4 * j;
                float4 wv = *reinterpret_cast<const float4*>(
                    W + (size_t)(oh * 64 + o) * CH + ch * 64 + c4 * 4);
                Wt[c4*4+0][o] = wv.x; Wt[c4*4+1][o] = wv.y;
                Wt[c4*4+2][o] = wv.z; Wt[c4*4+3][o] = wv.w;
            }
        }
        {
            const int nchunk = tid & 15, cb = tid >> 4;
            #pragma unroll
            for (int j = 0; j < 4; ++j) {
                const int c = cb + 16 * j;
                float4 v = *reinterpret_cast<const float4*>(
                    fsrc + (size_t)(ch * 64 + c) * NTOK + nb + nchunk * 4);
                *reinterpret_cast<float4*>(&fs[c][nchunk * 4]) = v;
            }
        }
        __syncthreads();
        #pragma unroll 4
        for (int c = 0; c < 64; ++c) {
            float4 wv = *reinterpret_cast<const float4*>(&Wt[c][o0]);
            float4 fv = *reinterpret_cast<const float4*>(&fs[c][nn0]);
            acc[0][0] = fmaf(wv.x, fv.x, acc[0][0]); acc[0][1] = fmaf(wv.x, fv.y, acc[0][1]);
            acc[0][2] = fmaf(wv.x, fv.z, acc[0][2]); acc[0][3] = fmaf(wv.x, fv.w, acc[0][3]);
            acc[1][0] = fmaf(wv.y, fv.x, acc[1][0]); acc[1][1] = fmaf(wv.y, fv.y, acc[1][1]);
            acc[1][2] = fmaf(wv.y, fv.z, acc[1][2]); acc[1][3] = fmaf(wv.y, fv.w, acc[1][3]);
            acc[2][0] = fmaf(wv.z, fv.x, acc[2][0]); acc[2][1] = fmaf(wv.z, fv.y, acc[2][1]);
            acc[2][2] = fmaf(wv.z, fv.z, acc[2][2]); acc[2][3] = fmaf(wv.z, fv.w, acc[2][3]);
            acc[3][0] = fmaf(wv.w, fv.x, acc[3][0]); acc[3][1] = fmaf(wv.w, fv.y, acc[3][1]);
            acc[3][2] = fmaf(wv.w, fv.z, acc[3][2]); acc[3][3] = fmaf(wv.w, fv.w, acc[3][3]);
        }
    }

    const int og0 = oh * 64 + o0;
    const int h = og0 >> 5, d0 = og0 & 31;
    const int ng = nb + nn0;
    if (t == 2) {
        const int off = ng & 15;                      // 0,4,8,12
        const int ng2 = (ng & ~15) + ((off & 4) << 1) + ((off & 8) >> 1);
        #pragma unroll
        for (int i = 0; i < 4; ++i) {
            ushort4 pk;
            pk.x = __builtin_bit_cast(unsigned short, (__bf16)acc[i][0]);
            pk.y = __builtin_bit_cast(unsigned short, (__bf16)acc[i][1]);
            pk.z = __builtin_bit_cast(unsigned short, (__bf16)acc[i][2]);
            pk.w = __builtin_bit_cast(unsigned short, (__bf16)acc[i][3]);
            *reinterpret_cast<ushort4*>(V2 + (size_t)(h * HDIM + d0 + i) * NKEY + m * NTOK + ng2) = pk;
        }
    } else {
        const float sc = (t == 0) ? QSC : 1.0f;
        unsigned short* base = ((t == 0) ? Qb : Kb)
            + (((size_t)(m * NHD + h)) * NTOK + ng) * HDIM + d0;
        #pragma unroll
        for (int j = 0; j < 4; ++j) {
            unsigned short* row = base + (size_t)j * HDIM;
            *reinterpret_cast<unsigned int*>(row)     = pkbf(acc[0][j] * sc, acc[1][j] * sc);
            *reinterpret_cast<unsigned int*>(row + 2) = pkbf(acc[2][j] * sc, acc[3][j] * sc);
        }
    }
}

// ---------------------------------------------------------------------------
// Kernel 2: MFMA cross-modal attention, 1728 blocks x 4 waves (256 thr).
// IDENTICAL to R10 except __launch_bounds__(256, 6): R10's (256,8) capped
// the allocator at ~VGPR=32 and spilled the 32-reg MFMA accumulators to
// scratch (global) -> 185 MB of spill traffic, 117 us. (256,6) gives an
// ~85-VGPR budget (kernel needs ~56) while keeping 6 blocks/CU resident
// (24 waves/CU, 1.8x R9's residency).
// bid: slot=bid&7 -> (h=slot>>1, ko=slot&1); rest=bid>>3: qb=rest%108,
// kseg=rest/108. Wave w: qslot=w&1, ks=w>>1 (km=2ko+ks); 27 tiles x 32 keys.
// Swizzles (bank-enumerated): K chunk ^= (key>>1)&3, V chunk ^= d&3;
// pre-applied on glds SOURCE, involution on ds_read. ones-B denominator.
// ---------------------------------------------------------------------------
__global__ __launch_bounds__(256, 6) void attn_kernel(
    const unsigned short* __restrict__ Qb, const unsigned short* __restrict__ Kb,
    const unsigned short* __restrict__ V2,
    float* __restrict__ accT, float* __restrict__ sR)
{
    __shared__ __align__(16) unsigned short smAll[2][2][2][1024]; // [buf][ks][K/V] 16 KB

    const int tid  = threadIdx.x;
    const int lane = tid & 63;
    const int w    = tid >> 6;        // 0..3
    const int qslot = w & 1;
    const int ks    = w >> 1;
    const int l31  = lane & 31;
    const int hi   = lane >> 5;

    const int bid  = blockIdx.x;
    const int slot = bid & 7;              // XCD slot
    const int h    = slot >> 1;
    const int ko   = slot & 1;
    const int rest = bid >> 3;             // 0..215
    const int qb   = rest % 108;
    const int kseg = rest / 108;           // 0..1
    const int qtile = qb * 2 + qslot;      // 0..215
    const int qg0  = qtile * 32;
    const int im   = qg0 / NTOK;
    const int n0   = qg0 % NTOK;
    const int km   = ko * 2 + ks;
    const int p    = kseg * 2 + ko;        // partial slot 0..3

    // Q fragments (pre-scaled by QSC)
    const unsigned short* qp = Qb + (((size_t)(im * NHD + h)) * NTOK + n0 + l31) * HDIM + hi * 8;
    const bf16x8 qf0 = ldb8(qp);
    const bf16x8 qf1 = ldb8(qp + 16);

    // --- staging sources (this wave's 2 glds per tile, inverse-swizzled) ---
    const int rk0 = qslot * 16 + (lane >> 2);            // K tile row (key)
    const int ck0 = (lane & 3) ^ ((rk0 >> 1) & 3);
    const unsigned short* gk0 = Kb
        + (((size_t)(km * NHD + h)) * NTOK + kseg * 864 + rk0) * HDIM + ck0 * 8;
    const int dv0 = qslot * 16 + (lane >> 2);            // V tile row (d)
    const int cv0 = (lane & 3) ^ (dv0 & 3);
    const unsigned short* gv0 = V2
        + ((size_t)(h * HDIM + dv0)) * NKEY + km * NTOK + kseg * 864 + cv0 * 8;

    // --- LDS read offsets (shorts), swizzle involution applied ---
    const int fK = (l31 >> 1) & 3, fV = l31 & 3;
    const int kA0 = l31 * 32 + ((hi ^ fK) << 3);
    const int kB0 = l31 * 32 + (((2 + hi) ^ fK) << 3);
    const int vo0 = l31 * 32 + ((hi ^ fV) << 3);
    const int vo1 = l31 * 32 + (((2 + hi) ^ fV) << 3);

    f32x16 z;
    #pragma unroll
    for (int r = 0; r < 16; ++r) z[r] = 0.f;
    f32x16 o_acc = z, s_acc = z;
    bf16x8 onesv;
    #pragma unroll
    for (int j = 0; j < 8; ++j) onesv[j] = (__bf16)1.0f;

    // stage next tile into buffer bb (2 glds; pointers advance)
    #define STAGE(bb) do {                                      \
        glds16(gk0, &smAll[bb][ks][0][0] + qslot * 512);        \
        glds16(gv0, &smAll[bb][ks][1][0] + qslot * 512);        \
        gk0 += 1024; gv0 += 32;                                 \
    } while (0)

    STAGE(0);                 // tile 0
    __syncthreads();

    int buf = 0;
    for (int t = 0; t < NT; ++t) {
        if (t + 1 < NT) STAGE(buf ^ 1);
        const unsigned short* Kl = &smAll[buf][ks][0][0];
        const unsigned short* Vl = &smAll[buf][ks][1][0];

        bf16x8 k0 = ldb8(Kl + kA0);
        bf16x8 k1 = ldb8(Kl + kB0);
        f32x16 c = __builtin_amdgcn_mfma_f32_32x32x16_bf16(k0, qf0, z, 0, 0, 0);
        c = __builtin_amdgcn_mfma_f32_32x32x16_bf16(k1, qf1, c, 0, 0, 0);

        float e[16];
        #pragma unroll
        for (int r = 0; r < 16; ++r) e[r] = EXP2(c[r]);
        bf16x8 pa0, pa1;
        #pragma unroll
        for (int j = 0; j < 8; ++j) { pa0[j] = (__bf16)e[j]; pa1[j] = (__bf16)e[8 + j]; }

        bf16x8 v0 = ldb8(Vl + vo0);
        bf16x8 v1 = ldb8(Vl + vo1);

        o_acc = __builtin_amdgcn_mfma_f32_32x32x16_bf16(pa0, v0, o_acc, 0, 0, 0);
        o_acc = __builtin_amdgcn_mfma_f32_32x32x16_bf16(pa1, v1, o_acc, 0, 0, 0);
        s_acc = __builtin_amdgcn_mfma_f32_32x32x16_bf16(pa0, onesv, s_acc, 0, 0, 0);
        s_acc = __builtin_amdgcn_mfma_f32_32x32x16_bf16(pa1, onesv, s_acc, 0, 0, 0);

        __syncthreads();
        buf ^= 1;
    }
    #undef STAGE

    // --- epilogue: combine ks pair in LDS [64 q][33] (s in col 32) ---
    float* accf = (float*)&smAll[0][0][0][0];    // 64*33*4 = 8.4 KB (reuse)
    if (ks == 1) {
        #pragma unroll
        for (int r = 0; r < 16; ++r) {
            const int qrow = (r & 3) + 8 * (r >> 2) + 4 * hi;
            accf[(qslot * 32 + qrow) * 33 + l31] = o_acc[r];
            if (l31 == 0) accf[(qslot * 32 + qrow) * 33 + 32] = s_acc[r];
        }
    }
    __syncthreads();
    if (ks == 0) {
        #pragma unroll
        for (int r = 0; r < 16; ++r) {
            const int qrow = (r & 3) + 8 * (r >> 2) + 4 * hi;
            accf[(qslot * 32 + qrow) * 33 + l31] += o_acc[r];
            if (l31 == 0) accf[(qslot * 32 + qrow) * 33 + 32] += s_acc[r];
        }
    }
    __syncthreads();
    {
        const int q  = tid & 63;
        const int dq = tid >> 6;      // 0..3
        #pragma unroll
        for (int j = 0; j < 8; ++j) {
            const int d = dq * 8 + j;
            accT[((size_t)((p * 4 + h) * HDIM + d)) * NKEY + (size_t)qb * 64 + q]
                = accf[q * 33 + d];
        }
        if (tid < 64)
            sR[((size_t)(p * 4 + h)) * NKEY + (size_t)qb * 64 + tid] = accf[tid * 33 + 32];
    }
}

// ---------------------------------------------------------------------------
// Kernel 3: combine 4 key-partials + normalize + modality-sum.
// ---------------------------------------------------------------------------
__global__ __launch_bounds__(256) void norm_kernel(
    const float* __restrict__ accT, const float* __restrict__ sR,
    float* __restrict__ fused)
{
    const int idx = blockIdx.x * 256 + threadIdx.x;  // 0 .. 128*1728-1
    const int c = idx / NTOK;
    const int n = idx % NTOK;
    const int h = c >> 5, d = c & 31;
    float acc = 0.f;
    #pragma unroll
    for (int imq = 0; imq < MODS; ++imq) {
        const size_t q = (size_t)imq * NTOK + n;
        float s = 0.f, a = 0.f;
        #pragma unroll
        for (int pp = 0; pp < 4; ++pp) {
            s += sR[(size_t)(pp * 4 + h) * NKEY + q];
            a += accT[((size_t)((pp * 4 + h) * HDIM + d)) * NKEY + q];
        }
        acc = fmaf(a, 1.0f / s, acc);
    }
    fused[idx] = acc;
}

// ---------------------------------------------------------------------------
// Kernel 4: out-proj (Wout @ fused) + BatchNorm(eval) + ReLU, 2 tokens/thread
// ---------------------------------------------------------------------------
__global__ __launch_bounds__(256) void outproj_kernel(
    const float* __restrict__ fused, const float* __restrict__ Wout,
    const float* __restrict__ gamma, const float* __restrict__ beta,
    const float* __restrict__ mean,  const float* __restrict__ var,
    float* __restrict__ out)
{
    const int idx = blockIdx.x * 256 + threadIdx.x;  // 0 .. 128*864-1
    const int n2 = idx % (NTOK / 2);
    const int o  = idx / (NTOK / 2);
    const float* W     = Wout + (size_t)o * CH;
    const float* fbase = fused + n2 * 2;
    float a0 = 0.f, a1 = 0.f;
    #pragma unroll 8
    for (int c = 0; c < CH; c += 4) {
        float4 w4 = *reinterpret_cast<const float4*>(W + c);
        float2 r0 = *reinterpret_cast<const float2*>(fbase + (size_t)(c + 0) * NTOK);
        float2 r1 = *reinterpret_cast<const float2*>(fbase + (size_t)(c + 1) * NTOK);
        float2 r2 = *reinterpret_cast<const float2*>(fbase + (size_t)(c + 2) * NTOK);
        float2 r3 = *reinterpret_cast<const float2*>(fbase + (size_t)(c + 3) * NTOK);
        a0 = fmaf(w4.x, r0.x, a0); a0 = fmaf(w4.y, r1.x, a0);
        a0 = fmaf(w4.z, r2.x, a0); a0 = fmaf(w4.w, r3.x, a0);
        a1 = fmaf(w4.x, r0.y, a1); a1 = fmaf(w4.y, r1.y, a1);
        a1 = fmaf(w4.z, r2.y, a1); a1 = fmaf(w4.w, r3.y, a1);
    }
    float inv = gamma[o] * rsqrtf(var[o] + 1e-5f);
    float sh  = fmaf(-mean[o], inv, beta[o]);
    float2 y;
    y.x = fmaxf(fmaf(a0, inv, sh), 0.f);
    y.y = fmaxf(fmaf(a1, inv, sh), 0.f);
    *reinterpret_cast<float2*>(out + (size_t)o * NTOK + n2 * 2) = y;
}

// ---------------------------------------------------------------------------
extern "C" void kernel_launch(void* const* d_in, const int* in_sizes, int n_in,
                              void* d_out, int out_size, void* d_ws, size_t ws_size,
                              hipStream_t stream)
{
    const float* f0    = (const float*)d_in[0];
    const float* f1    = (const float*)d_in[1];
    const float* f2    = (const float*)d_in[2];
    const float* f3    = (const float*)d_in[3];
    const float* Wq    = (const float*)d_in[4];
    const float* Wk    = (const float*)d_in[5];
    const float* Wv    = (const float*)d_in[6];
    const float* Wout  = (const float*)d_in[7];
    const float* gamma = (const float*)d_in[8];
    const float* beta  = (const float*)d_in[9];
    const float* mean  = (const float*)d_in[10];
    const float* var   = (const float*)d_in[11];
    float* out = (float*)d_out;

    const size_t QKV = (size_t)MODS * NHD * NTOK * HDIM;   // 884736 elems
    unsigned short* Qb = (unsigned short*)d_ws;
    unsigned short* Kb = Qb + QKV;
    unsigned short* V2 = Kb + QKV;
    float* accT  = (float*)(V2 + QKV);          // [4p*4h*32d][6912 q] f32
    float* sR    = accT + (size_t)4 * NHD * HDIM * NKEY;   // [16][6912]
    float* fused = sR + (size_t)4 * NHD * NKEY;            // [CH][NTOK]

    proj_kernel<<<648, 256, 0, stream>>>(f0, f1, f2, f3, Wq, Wk, Wv, Qb, Kb, V2);
    attn_kernel<<<1728, 256, 0, stream>>>(Qb, Kb, V2, accT, sR);
    norm_kernel<<<(CH * NTOK) / 256, 256, 0, stream>>>(accT, sR, fused);
    outproj_kernel<<<(CH * NTOK / 2) / 256, 256, 0, stream>>>(
        fused, Wout, gamma, beta, mean, var, out);
}

// Round 12
// 76.449 us; speedup vs baseline: 1.7794x; 1.0194x over previous
//
#include <hip/hip_runtime.h>

#define MODS 4
#define CH   128
#define NHD  4
#define HDIM 32
#define NTOK 1728
#define NKEY (MODS*NTOK)        // 6912
#define NT   27                 // 32-key tiles per 864-key segment
// Q is pre-scaled by 1/sqrt(32) * log2(e); folded into Wq at prep time.
#define QSC (0.17677669529663687f * 1.4426950408889634f)

#ifndef __has_builtin
#define __has_builtin(x) 0
#endif
#if __has_builtin(__builtin_amdgcn_exp2f)
#define EXP2(x) __builtin_amdgcn_exp2f(x)
#else
#define EXP2(x) __expf(0.69314718055994531f * (x))
#endif

typedef __bf16 bf16x8 __attribute__((ext_vector_type(8)));
typedef float  f32x16 __attribute__((ext_vector_type(16)));

__device__ inline bf16x8 ldb8(const unsigned short* p) {
    return *reinterpret_cast<const bf16x8*>(p);
}
__device__ inline unsigned short bfc(float x) {
    return __builtin_bit_cast(unsigned short, (__bf16)x);
}
// async global->LDS, 16B per lane; LDS dest = uniform base + lane*16
__device__ inline void glds16(const unsigned short* g, unsigned short* l) {
    __builtin_amdgcn_global_load_lds(
        (const __attribute__((address_space(1))) unsigned int*)(g),
        (__attribute__((address_space(3))) unsigned int*)(l), 16, 0, 0);
}

// ---------------------------------------------------------------------------
// Kernel 0: prep — (a) f[m][c][n] -> fbT[m][n][c] bf16 via LDS transpose;
// (b) W{q,k,v} fp32 -> Wb[t][m][o][c] bf16, QSC folded into Wq.
// ---------------------------------------------------------------------------
__global__ __launch_bounds__(256) void prep_kernel(
    const float* __restrict__ f0, const float* __restrict__ f1,
    const float* __restrict__ f2, const float* __restrict__ f3,
    const float* __restrict__ Wq, const float* __restrict__ Wk,
    const float* __restrict__ Wv,
    unsigned short* __restrict__ fbT, unsigned short* __restrict__ Wb)
{
    const int tid = threadIdx.x;
    const int bid = blockIdx.x;
    if (bid < 216) {                       // f transpose: 4m x 2cb x 27nb
        __shared__ float tile[64][65];
        const int m  = bid / 54;
        const int r  = bid % 54;
        const int cb = (r / 27) * 64;
        const int nb = (r % 27) * 64;
        const float* fsrc = (m == 0) ? f0 : (m == 1) ? f1 : (m == 2) ? f2 : f3;
        const int n4 = tid & 15, cr = tid >> 4;
        #pragma unroll
        for (int j = 0; j < 4; ++j) {
            const int c = cr + 16 * j;
            float4 v = *reinterpret_cast<const float4*>(
                fsrc + (size_t)(cb + c) * NTOK + nb + n4 * 4);
            tile[c][n4*4+0] = v.x; tile[c][n4*4+1] = v.y;
            tile[c][n4*4+2] = v.z; tile[c][n4*4+3] = v.w;
        }
        __syncthreads();
        const int cq = tid & 15, nr0 = tid >> 4;
        #pragma unroll
        for (int j = 0; j < 4; ++j) {
            const int nr = nr0 + 16 * j;
            ushort4 pk;
            pk.x = bfc(tile[cq*4+0][nr]); pk.y = bfc(tile[cq*4+1][nr]);
            pk.z = bfc(tile[cq*4+2][nr]); pk.w = bfc(tile[cq*4+3][nr]);
            *reinterpret_cast<ushort4*>(
                fbT + ((size_t)m * NTOK + nb + nr) * CH + cb + cq * 4) = pk;
        }
    } else {                               // W convert: 24 blocks x 8192 elems
        const int wb = bid - 216;
        const size_t base = ((size_t)wb * 256 + tid) * 32;
        #pragma unroll
        for (int g = 0; g < 8; ++g) {
            const size_t i = base + g * 4;
            const int t = (int)(i >> 16);          // /65536
            const size_t off = i & 65535;
            const float* W = (t == 0) ? Wq : (t == 1) ? Wk : Wv;
            float4 v = *reinterpret_cast<const float4*>(W + off);
            const float sc = (t == 0) ? QSC : 1.0f;
            ushort4 pk;
            pk.x = bfc(v.x * sc); pk.y = bfc(v.y * sc);
            pk.z = bfc(v.z * sc); pk.w = bfc(v.w * sc);
            *reinterpret_cast<ushort4*>(Wb + i) = pk;
        }
    }
}

// ---------------------------------------------------------------------------
// Kernel 1: MFMA QKV projection. 648 blocks (12 tm x 54 ntile) x 4 waves.
// Wave w = 32-o tile; D[o][n] = sum_c W[o][c] f[c][n] via 8 chained
// mfma_32x32x16_bf16 (A = Wb row-frags, B = fbT row-frags; both contiguous
// 16B lane loads from L2 — same operand convention verified in attn).
// Epilogue through padded LDS [128][33] -> coalesced bf16 stores:
// Qb/Kb [m][h][n][32] (Q pre-scaled via Wq); V2 [h][32d][key] with the
// 16-window fragment permute {0,4,8,12}->{0,8,4,12} (4-key granules).
// ---------------------------------------------------------------------------
__global__ __launch_bounds__(256) void proj_kernel(
    const unsigned short* __restrict__ Wb, const unsigned short* __restrict__ fbT,
    unsigned short* __restrict__ Qb, unsigned short* __restrict__ Kb,
    unsigned short* __restrict__ V2)
{
    __shared__ __align__(16) float accf[128 * 33];   // 16.9 KB

    const int tid = threadIdx.x;
    const int lane = tid & 63;
    const int w    = tid >> 6;          // o-tile 0..3
    const int l31  = lane & 31;
    const int hi   = lane >> 5;

    const int bid = blockIdx.x;
    const int tm  = bid / 54;           // 0..11
    const int nb  = (bid % 54) * 32;
    const int t   = tm >> 2, m = tm & 3;

    const unsigned short* Wrow = Wb + (((size_t)tm * CH) + w * 32 + l31) * CH + hi * 8;
    const unsigned short* Frow = fbT + ((size_t)m * NTOK + nb + l31) * CH + hi * 8;

    f32x16 acc;
    #pragma unroll
    for (int r = 0; r < 16; ++r) acc[r] = 0.f;
    #pragma unroll
    for (int cc = 0; cc < 8; ++cc) {
        bf16x8 a = ldb8(Wrow + cc * 16);
        bf16x8 b = ldb8(Frow + cc * 16);
        acc = __builtin_amdgcn_mfma_f32_32x32x16_bf16(a, b, acc, 0, 0, 0);
    }
    #pragma unroll
    for (int r = 0; r < 16; ++r) {
        const int orow = w * 32 + (r & 3) + 8 * (r >> 2) + 4 * hi;
        accf[orow * 33 + l31] = acc[r];
    }
    __syncthreads();

    if (t < 2) {
        // Qb/Kb: [ (m*4+h) ][ n ][ 32 d ], 8B per thread-store, coalesced
        unsigned short* dstb = (t == 0) ? Qb : Kb;
        const int nl = tid >> 3, dp = (tid & 7) * 4;
        #pragma unroll
        for (int h = 0; h < 4; ++h) {
            ushort4 pk;
            pk.x = bfc(accf[(h * 32 + dp + 0) * 33 + nl]);
            pk.y = bfc(accf[(h * 32 + dp + 1) * 33 + nl]);
            pk.z = bfc(accf[(h * 32 + dp + 2) * 33 + nl]);
            pk.w = bfc(accf[(h * 32 + dp + 3) * 33 + nl]);
            *reinterpret_cast<ushort4*>(
                dstb + (((size_t)(m * NHD + h)) * NTOK + nb + nl) * HDIM + dp) = pk;
        }
    } else {
        // V2: row = h*32+d (0..127), 16-key window per (row, half)
        const int row = tid >> 1, half = tid & 1;
        const int nw = half * 16;
        unsigned short* dst = V2 + (size_t)row * NKEY + (size_t)m * NTOK + nb + nw;
        const float* src = &accf[row * 33 + nw];
        ushort4 p0, p1, p2, p3;
        p0.x = bfc(src[0]);  p0.y = bfc(src[1]);  p0.z = bfc(src[2]);  p0.w = bfc(src[3]);
        p1.x = bfc(src[8]);  p1.y = bfc(src[9]);  p1.z = bfc(src[10]); p1.w = bfc(src[11]);
        p2.x = bfc(src[4]);  p2.y = bfc(src[5]);  p2.z = bfc(src[6]);  p2.w = bfc(src[7]);
        p3.x = bfc(src[12]); p3.y = bfc(src[13]); p3.z = bfc(src[14]); p3.w = bfc(src[15]);
        *reinterpret_cast<ushort4*>(dst + 0)  = p0;   // n 0-3   -> pos 0-3
        *reinterpret_cast<ushort4*>(dst + 4)  = p1;   // n 8-11  -> pos 4-7
        *reinterpret_cast<ushort4*>(dst + 8)  = p2;   // n 4-7   -> pos 8-11
        *reinterpret_cast<ushort4*>(dst + 12) = p3;   // n 12-15 -> pos 12-15
    }
}

// ---------------------------------------------------------------------------
// Kernel 2: MFMA cross-modal attention — byte-identical to R11.
// 1728 blocks x 4 waves; slot=bid&7 -> (h,ko); qb=rest%108, kseg=rest/108.
// Swizzles (bank-enumerated): K chunk ^= (key>>1)&3, V chunk ^= d&3;
// pre-applied on glds SOURCE, involution on ds_read. ones-B denominator.
// ---------------------------------------------------------------------------
__global__ __launch_bounds__(256, 6) void attn_kernel(
    const unsigned short* __restrict__ Qb, const unsigned short* __restrict__ Kb,
    const unsigned short* __restrict__ V2,
    float* __restrict__ accT, float* __restrict__ sR)
{
    __shared__ __align__(16) unsigned short smAll[2][2][2][1024]; // 16 KB

    const int tid  = threadIdx.x;
    const int lane = tid & 63;
    const int w    = tid >> 6;        // 0..3
    const int qslot = w & 1;
    const int ks    = w >> 1;
    const int l31  = lane & 31;
    const int hi   = lane >> 5;

    const int bid  = blockIdx.x;
    const int slot = bid & 7;              // XCD slot
    const int h    = slot >> 1;
    const int ko   = slot & 1;
    const int rest = bid >> 3;             // 0..215
    const int qb   = rest % 108;
    const int kseg = rest / 108;           // 0..1
    const int qtile = qb * 2 + qslot;      // 0..215
    const int qg0  = qtile * 32;
    const int im   = qg0 / NTOK;
    const int n0   = qg0 % NTOK;
    const int km   = ko * 2 + ks;
    const int p    = kseg * 2 + ko;        // partial slot 0..3

    const unsigned short* qp = Qb + (((size_t)(im * NHD + h)) * NTOK + n0 + l31) * HDIM + hi * 8;
    const bf16x8 qf0 = ldb8(qp);
    const bf16x8 qf1 = ldb8(qp + 16);

    const int rk0 = qslot * 16 + (lane >> 2);
    const int ck0 = (lane & 3) ^ ((rk0 >> 1) & 3);
    const unsigned short* gk0 = Kb
        + (((size_t)(km * NHD + h)) * NTOK + kseg * 864 + rk0) * HDIM + ck0 * 8;
    const int dv0 = qslot * 16 + (lane >> 2);
    const int cv0 = (lane & 3) ^ (dv0 & 3);
    const unsigned short* gv0 = V2
        + ((size_t)(h * HDIM + dv0)) * NKEY + km * NTOK + kseg * 864 + cv0 * 8;

    const int fK = (l31 >> 1) & 3, fV = l31 & 3;
    const int kA0 = l31 * 32 + ((hi ^ fK) << 3);
    const int kB0 = l31 * 32 + (((2 + hi) ^ fK) << 3);
    const int vo0 = l31 * 32 + ((hi ^ fV) << 3);
    const int vo1 = l31 * 32 + (((2 + hi) ^ fV) << 3);

    f32x16 z;
    #pragma unroll
    for (int r = 0; r < 16; ++r) z[r] = 0.f;
    f32x16 o_acc = z, s_acc = z;
    bf16x8 onesv;
    #pragma unroll
    for (int j = 0; j < 8; ++j) onesv[j] = (__bf16)1.0f;

    #define STAGE(bb) do {                                      \
        glds16(gk0, &smAll[bb][ks][0][0] + qslot * 512);        \
        glds16(gv0, &smAll[bb][ks][1][0] + qslot * 512);        \
        gk0 += 1024; gv0 += 32;                                 \
    } while (0)

    STAGE(0);
    __syncthreads();

    int buf = 0;
    for (int t = 0; t < NT; ++t) {
        if (t + 1 < NT) STAGE(buf ^ 1);
        const unsigned short* Kl = &smAll[buf][ks][0][0];
        const unsigned short* Vl = &smAll[buf][ks][1][0];

        bf16x8 k0 = ldb8(Kl + kA0);
        bf16x8 k1 = ldb8(Kl + kB0);
        f32x16 c = __builtin_amdgcn_mfma_f32_32x32x16_bf16(k0, qf0, z, 0, 0, 0);
        c = __builtin_amdgcn_mfma_f32_32x32x16_bf16(k1, qf1, c, 0, 0, 0);

        float e[16];
        #pragma unroll
        for (int r = 0; r < 16; ++r) e[r] = EXP2(c[r]);
        bf16x8 pa0, pa1;
        #pragma unroll
        for (int j = 0; j < 8; ++j) { pa0[j] = (__bf16)e[j]; pa1[j] = (__bf16)e[8 + j]; }

        bf16x8 v0 = ldb8(Vl + vo0);
        bf16x8 v1 = ldb8(Vl + vo1);

        o_acc = __builtin_amdgcn_mfma_f32_32x32x16_bf16(pa0, v0, o_acc, 0, 0, 0);
        o_acc = __builtin_amdgcn_mfma_f32_32x32x16_bf16(pa1, v1, o_acc, 0, 0, 0);
        s_acc = __builtin_amdgcn_mfma_f32_32x32x16_bf16(pa0, onesv, s_acc, 0, 0, 0);
        s_acc = __builtin_amdgcn_mfma_f32_32x32x16_bf16(pa1, onesv, s_acc, 0, 0, 0);

        __syncthreads();
        buf ^= 1;
    }
    #undef STAGE

    float* accfL = (float*)&smAll[0][0][0][0];   // 64*33*4 = 8.4 KB (reuse)
    if (ks == 1) {
        #pragma unroll
        for (int r = 0; r < 16; ++r) {
            const int qrow = (r & 3) + 8 * (r >> 2) + 4 * hi;
            accfL[(qslot * 32 + qrow) * 33 + l31] = o_acc[r];
            if (l31 == 0) accfL[(qslot * 32 + qrow) * 33 + 32] = s_acc[r];
        }
    }
    __syncthreads();
    if (ks == 0) {
        #pragma unroll
        for (int r = 0; r < 16; ++r) {
            const int qrow = (r & 3) + 8 * (r >> 2) + 4 * hi;
            accfL[(qslot * 32 + qrow) * 33 + l31] += o_acc[r];
            if (l31 == 0) accfL[(qslot * 32 + qrow) * 33 + 32] += s_acc[r];
        }
    }
    __syncthreads();
    {
        const int q  = tid & 63;
        const int dq = tid >> 6;
        #pragma unroll
        for (int j = 0; j < 8; ++j) {
            const int d = dq * 8 + j;
            accT[((size_t)((p * 4 + h) * HDIM + d)) * NKEY + (size_t)qb * 64 + q]
                = accfL[q * 33 + d];
        }
        if (tid < 64)
            sR[((size_t)(p * 4 + h)) * NKEY + (size_t)qb * 64 + tid] = accfL[tid * 33 + 32];
    }
}

// ---------------------------------------------------------------------------
// Kernel 3: combine 4 key-partials + normalize + modality-sum.
// ---------------------------------------------------------------------------
__global__ __launch_bounds__(256) void norm_kernel(
    const float* __restrict__ accT, const float* __restrict__ sR,
    float* __restrict__ fused)
{
    const int idx = blockIdx.x * 256 + threadIdx.x;  // 0 .. 128*1728-1
    const int c = idx / NTOK;
    const int n = idx % NTOK;
    const int h = c >> 5, d = c & 31;
    float acc = 0.f;
    #pragma unroll
    for (int imq = 0; imq < MODS; ++imq) {
        const size_t q = (size_t)imq * NTOK + n;
        float s = 0.f, a = 0.f;
        #pragma unroll
        for (int pp = 0; pp < 4; ++pp) {
            s += sR[(size_t)(pp * 4 + h) * NKEY + q];
            a += accT[((size_t)((pp * 4 + h) * HDIM + d)) * NKEY + q];
        }
        acc = fmaf(a, 1.0f / s, acc);
    }
    fused[idx] = acc;
}

// ---------------------------------------------------------------------------
// Kernel 4: out-proj (Wout @ fused) + BatchNorm(eval) + ReLU, 2 tokens/thread
// ---------------------------------------------------------------------------
__global__ __launch_bounds__(256) void outproj_kernel(
    const float* __restrict__ fused, const float* __restrict__ Wout,
    const float* __restrict__ gamma, const float* __restrict__ beta,
    const float* __restrict__ mean,  const float* __restrict__ var,
    float* __restrict__ out)
{
    const int idx = blockIdx.x * 256 + threadIdx.x;  // 0 .. 128*864-1
    const int n2 = idx % (NTOK / 2);
    const int o  = idx / (NTOK / 2);
    const float* W     = Wout + (size_t)o * CH;
    const float* fbase = fused + n2 * 2;
    float a0 = 0.f, a1 = 0.f;
    #pragma unroll 8
    for (int c = 0; c < CH; c += 4) {
        float4 w4 = *reinterpret_cast<const float4*>(W + c);
        float2 r0 = *reinterpret_cast<const float2*>(fbase + (size_t)(c + 0) * NTOK);
        float2 r1 = *reinterpret_cast<const float2*>(fbase + (size_t)(c + 1) * NTOK);
        float2 r2 = *reinterpret_cast<const float2*>(fbase + (size_t)(c + 2) * NTOK);
        float2 r3 = *reinterpret_cast<const float2*>(fbase + (size_t)(c + 3) * NTOK);
        a0 = fmaf(w4.x, r0.x, a0); a0 = fmaf(w4.y, r1.x, a0);
        a0 = fmaf(w4.z, r2.x, a0); a0 = fmaf(w4.w, r3.x, a0);
        a1 = fmaf(w4.x, r0.y, a1); a1 = fmaf(w4.y, r1.y, a1);
        a1 = fmaf(w4.z, r2.y, a1); a1 = fmaf(w4.w, r3.y, a1);
    }
    float inv = gamma[o] * rsqrtf(var[o] + 1e-5f);
    float sh  = fmaf(-mean[o], inv, beta[o]);
    float2 y;
    y.x = fmaxf(fmaf(a0, inv, sh), 0.f);
    y.y = fmaxf(fmaf(a1, inv, sh), 0.f);
    *reinterpret_cast<float2*>(out + (size_t)o * NTOK + n2 * 2) = y;
}

// ---------------------------------------------------------------------------
extern "C" void kernel_launch(void* const* d_in, const int* in_sizes, int n_in,
                              void* d_out, int out_size, void* d_ws, size_t ws_size,
                              hipStream_t stream)
{
    const float* f0    = (const float*)d_in[0];
    const float* f1    = (const float*)d_in[1];
    const float* f2    = (const float*)d_in[2];
    const float* f3    = (const float*)d_in[3];
    const float* Wq    = (const float*)d_in[4];
    const float* Wk    = (const float*)d_in[5];
    const float* Wv    = (const float*)d_in[6];
    const float* Wout  = (const float*)d_in[7];
    const float* gamma = (const float*)d_in[8];
    const float* beta  = (const float*)d_in[9];
    const float* mean  = (const float*)d_in[10];
    const float* var   = (const float*)d_in[11];
    float* out = (float*)d_out;

    const size_t QKV = (size_t)MODS * NHD * NTOK * HDIM;   // 884736 elems
    unsigned short* Qb  = (unsigned short*)d_ws;
    unsigned short* Kb  = Qb + QKV;
    unsigned short* V2  = Kb + QKV;
    unsigned short* fbT = V2 + QKV;                        // [m][n][c] bf16
    unsigned short* Wb  = fbT + QKV;                       // [3][4][128][128] bf16
    float* accT  = (float*)(Wb + (size_t)3 * MODS * CH * CH);
    float* sR    = accT + (size_t)4 * NHD * HDIM * NKEY;   // [16][6912]
    float* fused = sR + (size_t)4 * NHD * NKEY;            // [CH][NTOK]

    prep_kernel<<<240, 256, 0, stream>>>(f0, f1, f2, f3, Wq, Wk, Wv, fbT, Wb);
    proj_kernel<<<648, 256, 0, stream>>>(Wb, fbT, Qb, Kb, V2);
    attn_kernel<<<1728, 256, 0, stream>>>(Qb, Kb, V2, accT, sR);
    norm_kernel<<<(CH * NTOK) / 256, 256, 0, stream>>>(accT, sR, fused);
    outproj_kernel<<<(CH * NTOK / 2) / 256, 256, 0, stream>>>(
        fused, Wout, gamma, beta, mean, var, out);
}

// Round 13
// 70.815 us; speedup vs baseline: 1.9210x; 1.0796x over previous
//
#include <hip/hip_runtime.h>

#define MODS 4
#define CH   128
#define NHD  4
#define HDIM 32
#define NTOK 1728
#define NKEY (MODS*NTOK)        // 6912
#define NT   27                 // 32-key tiles per 864-key segment
// Q is pre-scaled by 1/sqrt(32) * log2(e); folded into Wq at prep time.
#define QSC (0.17677669529663687f * 1.4426950408889634f)

#ifndef __has_builtin
#define __has_builtin(x) 0
#endif
#if __has_builtin(__builtin_amdgcn_exp2f)
#define EXP2(x) __builtin_amdgcn_exp2f(x)
#else
#define EXP2(x) __expf(0.69314718055994531f * (x))
#endif

typedef __bf16 bf16x8 __attribute__((ext_vector_type(8)));
typedef float  f32x16 __attribute__((ext_vector_type(16)));

__device__ inline bf16x8 ldb8(const unsigned short* p) {
    return *reinterpret_cast<const bf16x8*>(p);
}
__device__ inline unsigned short bfc(float x) {
    return __builtin_bit_cast(unsigned short, (__bf16)x);
}
__device__ inline unsigned int pkbf(float a, float b) {
    return (unsigned int)bfc(a) | ((unsigned int)bfc(b) << 16);
}
// async global->LDS, 16B per lane; LDS dest = uniform base + lane*16
__device__ inline void glds16(const unsigned short* g, unsigned short* l) {
    __builtin_amdgcn_global_load_lds(
        (const __attribute__((address_space(1))) unsigned int*)(g),
        (__attribute__((address_space(3))) unsigned int*)(l), 16, 0, 0);
}

// ---------------------------------------------------------------------------
// Kernel 0: prepw — convert Wq(×QSC)/Wk/Wv -> Wb bf16 and Wout -> WbO bf16.
// 212992 elems = 52 blocks × 256 thr × 16 elems (regions are 16-aligned).
// ---------------------------------------------------------------------------
__global__ __launch_bounds__(256) void prepw_kernel(
    const float* __restrict__ Wq, const float* __restrict__ Wk,
    const float* __restrict__ Wv, const float* __restrict__ Wout,
    unsigned short* __restrict__ Wb, unsigned short* __restrict__ WbO)
{
    const int gid = blockIdx.x * 256 + threadIdx.x;   // 0..13311
    const size_t base = (size_t)gid * 16;
    const float* src; unsigned short* dst; float sc = 1.0f;
    if (base < 65536)       { src = Wq + base;            dst = Wb + base;  sc = QSC; }
    else if (base < 131072) { src = Wk + (base - 65536);  dst = Wb + base; }
    else if (base < 196608) { src = Wv + (base - 131072); dst = Wb + base; }
    else                    { src = Wout + (base - 196608); dst = WbO + (base - 196608); }
    #pragma unroll
    for (int g = 0; g < 4; ++g) {
        float4 v = *reinterpret_cast<const float4*>(src + g * 4);
        ushort4 pk;
        pk.x = bfc(v.x * sc); pk.y = bfc(v.y * sc);
        pk.z = bfc(v.z * sc); pk.w = bfc(v.w * sc);
        *reinterpret_cast<ushort4*>(dst + g * 4) = pk;
    }
}

// ---------------------------------------------------------------------------
// Kernel 1: fused transpose + MFMA QKV projection. 648 blocks (12tm × 54nt).
// Phase 1: threads read f[c][nb+n] directly from global (transposed access,
// 128B-coalesced across lanes), pack bf16 -> fT[32n][136c] in LDS.
// Phase 2: wave w = 32-o tile; A = Wb bf16 row-frags (global, L2-hot),
// B = fT row-frags (ds_read_b128); 8 chained mfma_32x32x16_bf16.
// Epilogue identical to verified R12: accf[128][33] -> Qb/Kb/V2 stores
// (V2 16-window fragment permute {0,4,8,12}->{0,8,4,12}).
// ---------------------------------------------------------------------------
__global__ __launch_bounds__(256) void proj_kernel(
    const float* __restrict__ f0, const float* __restrict__ f1,
    const float* __restrict__ f2, const float* __restrict__ f3,
    const unsigned short* __restrict__ Wb,
    unsigned short* __restrict__ Qb, unsigned short* __restrict__ Kb,
    unsigned short* __restrict__ V2)
{
    __shared__ __align__(16) unsigned short fT[32][136];  // 8.7 KB
    __shared__ __align__(16) float accf[128 * 33];        // 16.9 KB

    const int tid = threadIdx.x;
    const int lane = tid & 63;
    const int w    = tid >> 6;          // o-tile 0..3
    const int l31  = lane & 31;
    const int hi   = lane >> 5;

    const int bid = blockIdx.x;
    const int tm  = bid / 54;           // 0..11
    const int nb  = (bid % 54) * 32;
    const int t   = tm >> 2, m = tm & 3;

    const float* fsrc = (m == 0) ? f0 : (m == 1) ? f1 : (m == 2) ? f2 : f3;

    // --- phase 1: build B tile fT[n][c] bf16 ---
    {
        const int n = tid & 31, cg = tid >> 5;       // cg 0..7 (16 c each)
        float v[16];
        #pragma unroll
        for (int k = 0; k < 16; ++k)
            v[k] = fsrc[(size_t)(cg * 16 + k) * NTOK + nb + n];
        unsigned int* dst = reinterpret_cast<unsigned int*>(&fT[n][cg * 16]);
        #pragma unroll
        for (int j = 0; j < 8; ++j) dst[j] = pkbf(v[2 * j], v[2 * j + 1]);
    }
    __syncthreads();

    // --- phase 2: MFMA ---
    const unsigned short* Wrow = Wb + ((size_t)tm * CH + w * 32 + l31) * CH + hi * 8;
    f32x16 acc;
    #pragma unroll
    for (int r = 0; r < 16; ++r) acc[r] = 0.f;
    #pragma unroll
    for (int cc = 0; cc < 8; ++cc) {
        bf16x8 a = ldb8(Wrow + cc * 16);
        bf16x8 b = ldb8(&fT[l31][cc * 16 + hi * 8]);
        acc = __builtin_amdgcn_mfma_f32_32x32x16_bf16(a, b, acc, 0, 0, 0);
    }
    #pragma unroll
    for (int r = 0; r < 16; ++r) {
        const int orow = w * 32 + (r & 3) + 8 * (r >> 2) + 4 * hi;
        accf[orow * 33 + l31] = acc[r];
    }
    __syncthreads();

    if (t < 2) {
        unsigned short* dstb = (t == 0) ? Qb : Kb;
        const int nl = tid >> 3, dp = (tid & 7) * 4;
        #pragma unroll
        for (int h = 0; h < 4; ++h) {
            ushort4 pk;
            pk.x = bfc(accf[(h * 32 + dp + 0) * 33 + nl]);
            pk.y = bfc(accf[(h * 32 + dp + 1) * 33 + nl]);
            pk.z = bfc(accf[(h * 32 + dp + 2) * 33 + nl]);
            pk.w = bfc(accf[(h * 32 + dp + 3) * 33 + nl]);
            *reinterpret_cast<ushort4*>(
                dstb + (((size_t)(m * NHD + h)) * NTOK + nb + nl) * HDIM + dp) = pk;
        }
    } else {
        const int row = tid >> 1, half = tid & 1;
        const int nw = half * 16;
        unsigned short* dst = V2 + (size_t)row * NKEY + (size_t)m * NTOK + nb + nw;
        const float* src = &accf[row * 33 + nw];
        ushort4 p0, p1, p2, p3;
        p0.x = bfc(src[0]);  p0.y = bfc(src[1]);  p0.z = bfc(src[2]);  p0.w = bfc(src[3]);
        p1.x = bfc(src[8]);  p1.y = bfc(src[9]);  p1.z = bfc(src[10]); p1.w = bfc(src[11]);
        p2.x = bfc(src[4]);  p2.y = bfc(src[5]);  p2.z = bfc(src[6]);  p2.w = bfc(src[7]);
        p3.x = bfc(src[12]); p3.y = bfc(src[13]); p3.z = bfc(src[14]); p3.w = bfc(src[15]);
        *reinterpret_cast<ushort4*>(dst + 0)  = p0;
        *reinterpret_cast<ushort4*>(dst + 4)  = p1;
        *reinterpret_cast<ushort4*>(dst + 8)  = p2;
        *reinterpret_cast<ushort4*>(dst + 12) = p3;
    }
}

// ---------------------------------------------------------------------------
// Kernel 2: MFMA cross-modal attention — byte-identical to R11/R12.
// ---------------------------------------------------------------------------
__global__ __launch_bounds__(256, 6) void attn_kernel(
    const unsigned short* __restrict__ Qb, const unsigned short* __restrict__ Kb,
    const unsigned short* __restrict__ V2,
    float* __restrict__ accT, float* __restrict__ sR)
{
    __shared__ __align__(16) unsigned short smAll[2][2][2][1024]; // 16 KB

    const int tid  = threadIdx.x;
    const int lane = tid & 63;
    const int w    = tid >> 6;        // 0..3
    const int qslot = w & 1;
    const int ks    = w >> 1;
    const int l31  = lane & 31;
    const int hi   = lane >> 5;

    const int bid  = blockIdx.x;
    const int slot = bid & 7;              // XCD slot
    const int h    = slot >> 1;
    const int ko   = slot & 1;
    const int rest = bid >> 3;             // 0..215
    const int qb   = rest % 108;
    const int kseg = rest / 108;           // 0..1
    const int qtile = qb * 2 + qslot;      // 0..215
    const int qg0  = qtile * 32;
    const int im   = qg0 / NTOK;
    const int n0   = qg0 % NTOK;
    const int km   = ko * 2 + ks;
    const int p    = kseg * 2 + ko;        // partial slot 0..3

    const unsigned short* qp = Qb + (((size_t)(im * NHD + h)) * NTOK + n0 + l31) * HDIM + hi * 8;
    const bf16x8 qf0 = ldb8(qp);
    const bf16x8 qf1 = ldb8(qp + 16);

    const int rk0 = qslot * 16 + (lane >> 2);
    const int ck0 = (lane & 3) ^ ((rk0 >> 1) & 3);
    const unsigned short* gk0 = Kb
        + (((size_t)(km * NHD + h)) * NTOK + kseg * 864 + rk0) * HDIM + ck0 * 8;
    const int dv0 = qslot * 16 + (lane >> 2);
    const int cv0 = (lane & 3) ^ (dv0 & 3);
    const unsigned short* gv0 = V2
        + ((size_t)(h * HDIM + dv0)) * NKEY + km * NTOK + kseg * 864 + cv0 * 8;

    const int fK = (l31 >> 1) & 3, fV = l31 & 3;
    const int kA0 = l31 * 32 + ((hi ^ fK) << 3);
    const int kB0 = l31 * 32 + (((2 + hi) ^ fK) << 3);
    const int vo0 = l31 * 32 + ((hi ^ fV) << 3);
    const int vo1 = l31 * 32 + (((2 + hi) ^ fV) << 3);

    f32x16 z;
    #pragma unroll
    for (int r = 0; r < 16; ++r) z[r] = 0.f;
    f32x16 o_acc = z, s_acc = z;
    bf16x8 onesv;
    #pragma unroll
    for (int j = 0; j < 8; ++j) onesv[j] = (__bf16)1.0f;

    #define STAGE(bb) do {                                      \
        glds16(gk0, &smAll[bb][ks][0][0] + qslot * 512);        \
        glds16(gv0, &smAll[bb][ks][1][0] + qslot * 512);        \
        gk0 += 1024; gv0 += 32;                                 \
    } while (0)

    STAGE(0);
    __syncthreads();

    int buf = 0;
    for (int t = 0; t < NT; ++t) {
        if (t + 1 < NT) STAGE(buf ^ 1);
        const unsigned short* Kl = &smAll[buf][ks][0][0];
        const unsigned short* Vl = &smAll[buf][ks][1][0];

        bf16x8 k0 = ldb8(Kl + kA0);
        bf16x8 k1 = ldb8(Kl + kB0);
        f32x16 c = __builtin_amdgcn_mfma_f32_32x32x16_bf16(k0, qf0, z, 0, 0, 0);
        c = __builtin_amdgcn_mfma_f32_32x32x16_bf16(k1, qf1, c, 0, 0, 0);

        float e[16];
        #pragma unroll
        for (int r = 0; r < 16; ++r) e[r] = EXP2(c[r]);
        bf16x8 pa0, pa1;
        #pragma unroll
        for (int j = 0; j < 8; ++j) { pa0[j] = (__bf16)e[j]; pa1[j] = (__bf16)e[8 + j]; }

        bf16x8 v0 = ldb8(Vl + vo0);
        bf16x8 v1 = ldb8(Vl + vo1);

        o_acc = __builtin_amdgcn_mfma_f32_32x32x16_bf16(pa0, v0, o_acc, 0, 0, 0);
        o_acc = __builtin_amdgcn_mfma_f32_32x32x16_bf16(pa1, v1, o_acc, 0, 0, 0);
        s_acc = __builtin_amdgcn_mfma_f32_32x32x16_bf16(pa0, onesv, s_acc, 0, 0, 0);
        s_acc = __builtin_amdgcn_mfma_f32_32x32x16_bf16(pa1, onesv, s_acc, 0, 0, 0);

        __syncthreads();
        buf ^= 1;
    }
    #undef STAGE

    float* accfL = (float*)&smAll[0][0][0][0];   // 64*33*4 = 8.4 KB (reuse)
    if (ks == 1) {
        #pragma unroll
        for (int r = 0; r < 16; ++r) {
            const int qrow = (r & 3) + 8 * (r >> 2) + 4 * hi;
            accfL[(qslot * 32 + qrow) * 33 + l31] = o_acc[r];
            if (l31 == 0) accfL[(qslot * 32 + qrow) * 33 + 32] = s_acc[r];
        }
    }
    __syncthreads();
    if (ks == 0) {
        #pragma unroll
        for (int r = 0; r < 16; ++r) {
            const int qrow = (r & 3) + 8 * (r >> 2) + 4 * hi;
            accfL[(qslot * 32 + qrow) * 33 + l31] += o_acc[r];
            if (l31 == 0) accfL[(qslot * 32 + qrow) * 33 + 32] += s_acc[r];
        }
    }
    __syncthreads();
    {
        const int q  = tid & 63;
        const int dq = tid >> 6;
        #pragma unroll
        for (int j = 0; j < 8; ++j) {
            const int d = dq * 8 + j;
            accT[((size_t)((p * 4 + h) * HDIM + d)) * NKEY + (size_t)qb * 64 + q]
                = accfL[q * 33 + d];
        }
        if (tid < 64)
            sR[((size_t)(p * 4 + h)) * NKEY + (size_t)qb * 64 + tid] = accfL[tid * 33 + 32];
    }
}

// ---------------------------------------------------------------------------
// Kernel 3: fused normalize + modality-sum + MFMA out-proj + BN + ReLU.
// 54 blocks (32-token tile each) × 256 thr.
// A: reciprocal softmax denominators -> rsL.  B: gather accT (each elem
// read once, float4 over n) -> bf16 fusedT[32n][136c] in LDS.
// C: wave w = 32-o tile; mfma(WbO, fusedT) -> BN -> ReLU -> out.
// ---------------------------------------------------------------------------
__global__ __launch_bounds__(256) void normout_kernel(
    const float* __restrict__ accT, const float* __restrict__ sR,
    const unsigned short* __restrict__ WbO,
    const float* __restrict__ gamma, const float* __restrict__ beta,
    const float* __restrict__ mean,  const float* __restrict__ var,
    float* __restrict__ out)
{
    __shared__ __align__(16) unsigned short fT2[32][136];  // 8.7 KB
    __shared__ float rsL[4][4][32];                        // 2 KB

    const int tid = threadIdx.x;
    const int nb  = blockIdx.x * 32;

    // --- phase A: rsL[h][imq][n] = 1 / sum_pp sR ---
    #pragma unroll
    for (int e2 = 0; e2 < 2; ++e2) {
        const int e = tid * 2 + e2;
        const int h = e >> 7, imq = (e >> 5) & 3, n = e & 31;
        float s = 0.f;
        #pragma unroll
        for (int pp = 0; pp < 4; ++pp)
            s += sR[(size_t)(pp * 4 + h) * NKEY + (size_t)imq * NTOK + nb + n];
        rsL[h][imq][n] = 1.0f / s;
    }
    __syncthreads();

    // --- phase B: fusedT[n][c] bf16 ---
    {
        const int n4 = (tid & 7) * 4;        // n base
        const int c0 = (tid >> 3) * 4;       // c base
        const int h  = c0 >> 5;
        float acc4[4][4] = {};               // [cc][nn]
        #pragma unroll
        for (int imq = 0; imq < 4; ++imq) {
            const size_t q = (size_t)imq * NTOK + nb + n4;
            float a[4][4] = {};
            #pragma unroll
            for (int pp = 0; pp < 4; ++pp) {
                #pragma unroll
                for (int cc = 0; cc < 4; ++cc) {
                    const int d = (c0 + cc) & 31;
                    float4 x = *reinterpret_cast<const float4*>(
                        accT + ((size_t)((pp * 4 + h) * HDIM + d)) * NKEY + q);
                    a[cc][0] += x.x; a[cc][1] += x.y; a[cc][2] += x.z; a[cc][3] += x.w;
                }
            }
            #pragma unroll
            for (int cc = 0; cc < 4; ++cc)
                #pragma unroll
                for (int nn = 0; nn < 4; ++nn)
                    acc4[cc][nn] = fmaf(a[cc][nn], rsL[h][imq][n4 + nn], acc4[cc][nn]);
        }
        #pragma unroll
        for (int nn = 0; nn < 4; ++nn) {
            ushort4 pk;
            pk.x = bfc(acc4[0][nn]); pk.y = bfc(acc4[1][nn]);
            pk.z = bfc(acc4[2][nn]); pk.w = bfc(acc4[3][nn]);
            *reinterpret_cast<ushort4*>(&fT2[n4 + nn][c0]) = pk;
        }
    }
    __syncthreads();

    // --- phase C: MFMA out-proj + BN + ReLU ---
    {
        const int lane = tid & 63;
        const int w    = tid >> 6;
        const int l31  = lane & 31;
        const int hi   = lane >> 5;
        const unsigned short* Arow = WbO + (size_t)(w * 32 + l31) * CH + hi * 8;
        f32x16 acc;
        #pragma unroll
        for (int r = 0; r < 16; ++r) acc[r] = 0.f;
        #pragma unroll
        for (int cc = 0; cc < 8; ++cc) {
            bf16x8 a = ldb8(Arow + cc * 16);
            bf16x8 b = ldb8(&fT2[l31][cc * 16 + hi * 8]);
            acc = __builtin_amdgcn_mfma_f32_32x32x16_bf16(a, b, acc, 0, 0, 0);
        }
        #pragma unroll
        for (int r = 0; r < 16; ++r) {
            const int orow = w * 32 + (r & 3) + 8 * (r >> 2) + 4 * hi;
            const float inv = gamma[orow] * rsqrtf(var[orow] + 1e-5f);
            const float sh  = fmaf(-mean[orow], inv, beta[orow]);
            out[(size_t)orow * NTOK + nb + l31] = fmaxf(fmaf(acc[r], inv, sh), 0.f);
        }
    }
}

// ---------------------------------------------------------------------------
extern "C" void kernel_launch(void* const* d_in, const int* in_sizes, int n_in,
                              void* d_out, int out_size, void* d_ws, size_t ws_size,
                              hipStream_t stream)
{
    const float* f0    = (const float*)d_in[0];
    const float* f1    = (const float*)d_in[1];
    const float* f2    = (const float*)d_in[2];
    const float* f3    = (const float*)d_in[3];
    const float* Wq    = (const float*)d_in[4];
    const float* Wk    = (const float*)d_in[5];
    const float* Wv    = (const float*)d_in[6];
    const float* Wout  = (const float*)d_in[7];
    const float* gamma = (const float*)d_in[8];
    const float* beta  = (const float*)d_in[9];
    const float* mean  = (const float*)d_in[10];
    const float* var   = (const float*)d_in[11];
    float* out = (float*)d_out;

    const size_t QKV = (size_t)MODS * NHD * NTOK * HDIM;   // 884736 elems
    unsigned short* Qb  = (unsigned short*)d_ws;
    unsigned short* Kb  = Qb + QKV;
    unsigned short* V2  = Kb + QKV;
    unsigned short* Wb  = V2 + QKV;             // 3*4*128*128 = 196608 bf16
    unsigned short* WbO = Wb + 196608;          // 128*128 = 16384 bf16
    float* accT = (float*)(WbO + 16384);        // [512 rows][6912 q] f32
    float* sR   = accT + (size_t)512 * NKEY;    // [16][6912] f32

    prepw_kernel<<<52, 256, 0, stream>>>(Wq, Wk, Wv, Wout, Wb, WbO);
    proj_kernel<<<648, 256, 0, stream>>>(f0, f1, f2, f3, Wb, Qb, Kb, V2);
    attn_kernel<<<1728, 256, 0, stream>>>(Qb, Kb, V2, accT, sR);
    normout_kernel<<<54, 256, 0, stream>>>(
        accT, sR, WbO, gamma, beta, mean, var, out);
}